// Round 1
// baseline (605.960 us; speedup 1.0000x reference)
//
#include <hip/hip_runtime.h>

// FIR band-pass, zero-phase, reflect_limited padding — direct correlation form.
// out[t] = sum_k g[k]*e[t+k], g[k]=h[412-k], e = reflect-extended x (see theory).
//
// T=10000, n_h=413, shift=(n_h-1)/2=206, n_edge=412.
// Tile = 2048 outputs/block, 256 threads, 8 outputs/thread (10000%8==0, 2048%8==0,
// tail tile 1808 = 226*8 -> no per-output masking).
//
// LDS e-tile stored 8-way interleaved: e_tile[i] at lds_e[(i&7)*S + (i>>3)], S=308.
// Thread t (base index 8t) reads index 8t+8m+j -> lds_e[j*S + (t+m)]: lane stride 1
// (conflict-free; 2-way over wave64 is free) and (j*S+m) is a compile-time/loop-scalar
// ds offset -> zero per-read address VALU.
// Sliding window w[8] is a circular register buffer; k-loop unrolled x8 so the
// rotation is static renaming (no v_mov shifts).

#define T_LEN   10000
#define N_H     413
#define N_EDGE  412
#define SHIFT   206          // (N_H-1)/2
#define TILE    2048
#define NTILES  5            // ceil(10000/2048)
#define S_SUB   308          // ceil((TILE+N_EDGE)/8) = ceil(2460/8)

__global__ __launch_bounds__(256, 4) void FilterBank_20624432955781_kernel(
    const float* __restrict__ x, const float* __restrict__ h, float* __restrict__ out) {
    __shared__ float lds_e[8 * S_SUB];   // 2464 floats
    __shared__ float lds_g[416];

    const int t = threadIdx.x;
    const int tile_start = blockIdx.x * TILE;
    const int row = blockIdx.y;
    const int n_out = min(TILE, T_LEN - tile_start);
    const int n_e = n_out + N_EDGE;

    const float* __restrict__ xrow = x + (size_t)row * T_LEN;

    // Stage reflect-extended e-tile into interleaved LDS. Stores are conflict-free
    // (banks (308*p + q) % 32 cover all 32 across 32 consecutive lanes).
    for (int idx = t; idx < n_e; idx += 256) {
        const int j = tile_start + idx;            // global e index, [0, 10412)
        float v;
        if (j < SHIFT)                 v = 2.0f * xrow[0]         - xrow[SHIFT - j];
        else if (j < T_LEN + SHIFT)    v = xrow[j - SHIFT];
        else                           v = 2.0f * xrow[T_LEN - 1] - xrow[2 * T_LEN + SHIFT - 2 - j];
        lds_e[(idx & 7) * S_SUB + (idx >> 3)] = v;
    }
    // Reversed filter (g[k] = h[412-k]).
    for (int k = t; k < N_H; k += 256) lds_g[k] = h[N_H - 1 - k];
    __syncthreads();

    float acc[8], w[8];
    #pragma unroll
    for (int r = 0; r < 8; ++r) acc[r] = 0.0f;

    const float* __restrict__ ebase = lds_e + t;   // thread-local column
    #pragma unroll
    for (int r = 0; r < 8; ++r) w[r] = ebase[r * S_SUB];   // w[r] = et[r]

    // Main: k = 8m+j, m=0..50 covers k=0..407.
    // Invariant entering step (m,j): w[(j+r)&7] = et[8m+j+r], r=0..7.
    for (int m = 0; m < 51; ++m) {
        #pragma unroll
        for (int j = 0; j < 8; ++j) {
            const float gk = lds_g[8 * m + j];     // uniform broadcast read
            #pragma unroll
            for (int r = 0; r < 8; ++r) acc[r] += gk * w[(j + r) & 7];
            w[j] = ebase[j * S_SUB + m + 1];       // refill with et[8(m+1)+j]
        }
    }
    // Remainder k = 408..412 (5 steps); window already holds et[408..415].
    #pragma unroll
    for (int j = 0; j < 5; ++j) {
        const float gk = lds_g[408 + j];
        #pragma unroll
        for (int r = 0; r < 8; ++r) acc[r] += gk * w[(j + r) & 7];
        if (j < 4) w[j] = ebase[j * S_SUB + 52];   // et[416+j], needed by later steps
    }

    if (t * 8 < n_out) {
        float* orow = out + (size_t)row * T_LEN + tile_start + t * 8;
        reinterpret_cast<float4*>(orow)[0] = make_float4(acc[0], acc[1], acc[2], acc[3]);
        reinterpret_cast<float4*>(orow)[1] = make_float4(acc[4], acc[5], acc[6], acc[7]);
    }
}

extern "C" void kernel_launch(void* const* d_in, const int* in_sizes, int n_in,
                              void* d_out, int out_size, void* d_ws, size_t ws_size,
                              hipStream_t stream) {
    const float* x = (const float*)d_in[0];   // [64,64,10000] fp32
    const float* h = (const float*)d_in[1];   // [413] fp32
    float* out = (float*)d_out;               // [64,64,10000] fp32
    dim3 grid(NTILES, 64 * 64);
    FilterBank_20624432955781_kernel<<<grid, dim3(256), 0, stream>>>(x, h, out);
}